// Round 6
// baseline (57.873 us; speedup 1.0000x reference)
//
#include <hip/hip_runtime.h>
#include <hip/hip_bf16.h>

#define BB 4
#define NN 4096
#define DD 128

typedef __attribute__((ext_vector_type(8))) short bf16x8;
typedef __attribute__((ext_vector_type(16))) float f32x16;

__device__ __forceinline__ unsigned short f2bf(float f) {
    unsigned u = __float_as_uint(f);
    return (unsigned short)((u + 0x7FFFu + ((u >> 16) & 1u)) >> 16);
}
__device__ __forceinline__ float bf2f(unsigned short s) {
    return __uint_as_float((unsigned)s << 16);
}
__device__ __forceinline__ unsigned pk2(float a, float b) {
    return (unsigned)f2bf(a) | ((unsigned)f2bf(b) << 16);
}

// ---------------------------------------------------------------------------
// Fragment-major layouts (shorts):
//   xbF: row-block rb = n>>5 (global over B*N), granule g = k>>3 (0..15):
//        addr = rb*4096 + g*256 + (n&31)*8 + (k&7)
//   vF:  per batch: d-block db = d>>5, m-granule g = m>>3 (0..511):
//        addr = b*524288 + db*131072 + g*256 + (d&31)*8 + (m&7)
//   wbF: j-block jb = j>>5, granule g = k>>3: jb*4096 + g*256 + (j&31)*8 + (k&7)
// ---------------------------------------------------------------------------

// prep: blocks 0..255 = x->bf16 frag-major (+transpose) + x2; blocks 256..263 = wt
__global__ __launch_bounds__(512) void prep_kernel(const float* __restrict__ x,
        const float* __restrict__ W, short* __restrict__ xbF,
        short* __restrict__ vF, short* __restrict__ wbF, float* __restrict__ x2) {
    if (blockIdx.x >= 256) {
        int t = (blockIdx.x - 256) * 512 + threadIdx.x;   // 0..4095
        int j = t >> 5, cq = t & 31;
        float4 v = *(const float4*)(W + j * 128 + cq * 4);
        uint2 pk; pk.x = pk2(v.x, v.y); pk.y = pk2(v.z, v.w);
        *(uint2*)(wbF + (j >> 5) * 4096 + (cq >> 1) * 256 + (j & 31) * 8 + (cq & 1) * 4) = pk;
        return;
    }
    __shared__ short Ls[64 * 136];
    int tid = threadIdx.x;
    int r = tid >> 3, cq = tid & 7;
    size_t rowg = (size_t)blockIdx.x * 64 + r;
    const float* xp = x + rowg * DD + cq * 16;
    short tmp[16];
    float s = 0.f;
    #pragma unroll
    for (int i = 0; i < 4; ++i) {
        float4 v = ((const float4*)xp)[i];
        unsigned short b0 = f2bf(v.x), b1 = f2bf(v.y), b2 = f2bf(v.z), b3 = f2bf(v.w);
        tmp[i*4+0] = (short)b0; tmp[i*4+1] = (short)b1;
        tmp[i*4+2] = (short)b2; tmp[i*4+3] = (short)b3;
        float f0 = bf2f(b0), f1 = bf2f(b1), f2 = bf2f(b2), f3 = bf2f(b3);
        s += f0*f0 + f1*f1 + f2*f2 + f3*f3;
    }
    #pragma unroll
    for (int c = 0; c < 2; ++c) {
        uint4 v = ((uint4*)tmp)[c];
        *(uint4*)(xbF + (rowg >> 5) * 4096 + (size_t)(cq * 2 + c) * 256 + (rowg & 31) * 8) = v;
        *(uint4*)(&Ls[r * 136 + cq * 16 + c * 8]) = v;
    }
    s += __shfl_xor(s, 1); s += __shfl_xor(s, 2); s += __shfl_xor(s, 4);
    if (cq == 0) x2[rowg] = s;
    __syncthreads();
    int d = tid & 127, q = tid >> 7;
    short arr[16];
    #pragma unroll
    for (int i = 0; i < 16; ++i) arr[i] = Ls[(q * 16 + i) * 136 + d];
    int blk = blockIdx.x, b = blk >> 6;
    int g0 = (blk & 63) * 8 + q * 2;
    size_t base = (size_t)b * 524288 + (size_t)(d >> 5) * 131072 + (size_t)(d & 31) * 8;
    *(uint4*)(vF + base + (size_t)g0 * 256)       = ((uint4*)arr)[0];
    *(uint4*)(vF + base + (size_t)(g0 + 1) * 256) = ((uint4*)arr)[1];
}

// ---------------------------------------------------------------------------
// attn: 256 blocks x 512 threads (8 waves), BARRIER-FREE main loop.
// Wave w owns m-slices s = w, w+8, ... (32 m-rows each), full n-tile 64.
// Live slices (rare) accumulate PV into shared f32 O via LDS atomics.
// ---------------------------------------------------------------------------
__global__ __launch_bounds__(512, 2) void attn_kernel(
        const short* __restrict__ xbF, const short* __restrict__ vF,
        const float* __restrict__ x2, const short* __restrict__ wbF,
        const float* __restrict__ log_sigmas, const float* __restrict__ pb,
        const float* __restrict__ x, const float* __restrict__ gamma,
        const float* __restrict__ beta, float* __restrict__ out) {
    __shared__ char smem[34816] __attribute__((aligned(128)));
    float* O_lds = (float*)smem;                       // [128 d][68 n]

    int tid = threadIdx.x, lane = tid & 63, w = tid >> 6;
    int l5 = lane & 31, hi = lane >> 5;

    int bid = (blockIdx.x & 7) * 32 + (blockIdx.x >> 3);  // XCD-bijective
    int b = bid >> 6, n0 = (bid & 63) * 64;

    const short* xf_b = xbF + (size_t)b * 524288;
    const short* vf_b = vF + (size_t)b * 524288;
    const float* x2b = x2 + (size_t)b * NN;

    #pragma unroll
    for (int i = 0; i < 17; ++i) O_lds[tid + 512 * i] = 0.f;

    float invd[4];
    #pragma unroll
    for (int h = 0; h < 4; ++h) {
        float sg = __expf(log_sigmas[h]);
        invd[h] = 1.0f / (2.0f * sg * sg + 1e-6f);
    }
    bool same = (invd[0] == invd[1]) && (invd[1] == invd[2]) && (invd[2] == invd[3]);
    float c0 = -invd[0];
    float invd_min = fminf(fminf(invd[0], invd[1]), fminf(invd[2], invd[3]));
    float thr = 30.0f / invd_min;

    // Q fragments for both n-halves
    bf16x8 qa[8], qb[8];
    {
        const short* qp = xf_b + (size_t)(n0 >> 5) * 4096;
        #pragma unroll
        for (int ck = 0; ck < 8; ++ck) {
            qa[ck] = *(const bf16x8*)(qp + (2 * ck + hi) * 256 + l5 * 8);
            qb[ck] = *(const bf16x8*)(qp + 4096 + (2 * ck + hi) * 256 + l5 * 8);
        }
    }
    float x2nA = x2b[n0 + l5], x2nB = x2b[n0 + 32 + l5];

    __syncthreads();   // O_lds zeroed

    bf16x8 kc[8];
    {
        const short* kp = xf_b + (size_t)w * 4096;
        #pragma unroll
        for (int ck = 0; ck < 8; ++ck)
            kc[ck] = *(const bf16x8*)(kp + (2 * ck + hi) * 256 + l5 * 8);
    }

    for (int s = w; s < 128; s += 8) {
        bf16x8 kn[8];
        if (s + 8 < 128) {
            const short* kp = xf_b + (size_t)(s + 8) * 4096;
            #pragma unroll
            for (int ck = 0; ck < 8; ++ck)
                kn[ck] = *(const bf16x8*)(kp + (2 * ck + hi) * 256 + l5 * 8);
        }
        float4 t0 = *(const float4*)(x2b + s * 32 + 4 * hi);
        float4 t1 = *(const float4*)(x2b + s * 32 + 8 + 4 * hi);
        float4 t2 = *(const float4*)(x2b + s * 32 + 16 + 4 * hi);
        float4 t3 = *(const float4*)(x2b + s * 32 + 24 + 4 * hi);
        float xmv[16];
        xmv[0]=t0.x; xmv[1]=t0.y; xmv[2]=t0.z; xmv[3]=t0.w;
        xmv[4]=t1.x; xmv[5]=t1.y; xmv[6]=t1.z; xmv[7]=t1.w;
        xmv[8]=t2.x; xmv[9]=t2.y; xmv[10]=t2.z; xmv[11]=t2.w;
        xmv[12]=t3.x; xmv[13]=t3.y; xmv[14]=t3.z; xmv[15]=t3.w;

        f32x16 SA, SB;
        #pragma unroll
        for (int i = 0; i < 16; ++i) { SA[i] = 0.f; SB[i] = 0.f; }
        #pragma unroll
        for (int ck = 0; ck < 8; ++ck) {
            SA = __builtin_amdgcn_mfma_f32_32x32x16_bf16(kc[ck], qa[ck], SA, 0, 0, 0);
            SB = __builtin_amdgcn_mfma_f32_32x32x16_bf16(kc[ck], qb[ck], SB, 0, 0, 0);
        }
        float dvA[16], dvB[16];
        #pragma unroll
        for (int i = 0; i < 16; ++i) {
            dvA[i] = x2nA + xmv[i] - 2.0f * SA[i];
            dvB[i] = x2nB + xmv[i] - 2.0f * SB[i];
        }
        float pmin = dvA[0];
        #pragma unroll
        for (int i = 1; i < 16; ++i) pmin = fminf(pmin, dvA[i]);
        #pragma unroll
        for (int i = 0; i < 16; ++i) pmin = fminf(pmin, dvB[i]);

        if (!__all(pmin > thr)) {
            float wA[16], wB[16];
            #pragma unroll
            for (int i = 0; i < 16; ++i) {
                float cA = fmaxf(dvA[i], 0.f), cB = fmaxf(dvB[i], 0.f);
                if (same) {
                    wA[i] = __expf(cA * c0);
                    wB[i] = __expf(cB * c0);
                } else {
                    wA[i] = 0.25f * (__expf(-cA * invd[0]) + __expf(-cA * invd[1]) +
                                     __expf(-cA * invd[2]) + __expf(-cA * invd[3]));
                    wB[i] = 0.25f * (__expf(-cB * invd[0]) + __expf(-cB * invd[1]) +
                                     __expf(-cB * invd[2]) + __expf(-cB * invd[3]));
                }
            }
            // pack granule quarters: granule G holds regs 4G..4G+3 (positions 4hi..4hi+3)
            unsigned pAlo[4], pAhi[4], pBlo[4], pBhi[4];
            #pragma unroll
            for (int G = 0; G < 4; ++G) {
                pAlo[G] = pk2(wA[4*G+0], wA[4*G+1]);
                pAhi[G] = pk2(wA[4*G+2], wA[4*G+3]);
                pBlo[G] = pk2(wB[4*G+0], wB[4*G+1]);
                pBhi[G] = pk2(wB[4*G+2], wB[4*G+3]);
            }
            uint4 fA[2], fB[2];
            #pragma unroll
            for (int ks = 0; ks < 2; ++ks) {
                unsigned oAl = hi ? pAlo[2*ks+1] : pAlo[2*ks];
                unsigned oAh = hi ? pAhi[2*ks+1] : pAhi[2*ks];
                unsigned sAl = hi ? pAlo[2*ks]   : pAlo[2*ks+1];
                unsigned sAh = hi ? pAhi[2*ks]   : pAhi[2*ks+1];
                unsigned rAl = __shfl_xor(sAl, 32);
                unsigned rAh = __shfl_xor(sAh, 32);
                fA[ks].x = hi ? rAl : oAl;  fA[ks].y = hi ? rAh : oAh;
                fA[ks].z = hi ? oAl : rAl;  fA[ks].w = hi ? oAh : rAh;
                unsigned oBl = hi ? pBlo[2*ks+1] : pBlo[2*ks];
                unsigned oBh = hi ? pBhi[2*ks+1] : pBhi[2*ks];
                unsigned sBl = hi ? pBlo[2*ks]   : pBlo[2*ks+1];
                unsigned sBh = hi ? pBhi[2*ks]   : pBhi[2*ks+1];
                unsigned rBl = __shfl_xor(sBl, 32);
                unsigned rBh = __shfl_xor(sBh, 32);
                fB[ks].x = hi ? rBl : oBl;  fB[ks].y = hi ? rBh : oBh;
                fB[ks].z = hi ? oBl : rBl;  fB[ks].w = hi ? oBh : rBh;
            }
            bf16x8 wfA0 = *(bf16x8*)&fA[0], wfA1 = *(bf16x8*)&fA[1];
            bf16x8 wfB0 = *(bf16x8*)&fB[0], wfB1 = *(bf16x8*)&fB[1];
            #pragma unroll
            for (int db = 0; db < 4; ++db) {
                const short* vp = vf_b + db * 131072 + (size_t)s * 4 * 256;
                bf16x8 v0 = *(const bf16x8*)(vp + (size_t)(0 + hi) * 256 + l5 * 8);
                bf16x8 v1 = *(const bf16x8*)(vp + (size_t)(2 + hi) * 256 + l5 * 8);
                f32x16 DA, DB;
                #pragma unroll
                for (int i = 0; i < 16; ++i) { DA[i] = 0.f; DB[i] = 0.f; }
                DA = __builtin_amdgcn_mfma_f32_32x32x16_bf16(v0, wfA0, DA, 0, 0, 0);
                DA = __builtin_amdgcn_mfma_f32_32x32x16_bf16(v1, wfA1, DA, 0, 0, 0);
                DB = __builtin_amdgcn_mfma_f32_32x32x16_bf16(v0, wfB0, DB, 0, 0, 0);
                DB = __builtin_amdgcn_mfma_f32_32x32x16_bf16(v1, wfB1, DB, 0, 0, 0);
                #pragma unroll
                for (int i = 0; i < 16; ++i) {
                    int droff = (i & 3) + 8 * (i >> 2) + 4 * hi;
                    atomicAdd(&O_lds[(db * 32 + droff) * 68 + l5], DA[i]);
                    atomicAdd(&O_lds[(db * 32 + droff) * 68 + 32 + l5], DB[i]);
                }
            }
        }
        if (s + 8 < 128) {
            #pragma unroll
            for (int ck = 0; ck < 8; ++ck) kc[ck] = kn[ck];
        }
    }

    __syncthreads();   // all LDS atomics done

    // ---- epilogue: proj MFMA from O_lds, then ELU + residual + LN ----
    int jq = w & 3, nh2 = w >> 2;
    bf16x8 af[8];
    #pragma unroll
    for (int ck = 0; ck < 8; ++ck) {
        unsigned u0, u1, u2, u3;
        {
            int dbase = ck * 16 + hi * 8;
            int nn = nh2 * 32 + l5;
            u0 = pk2(O_lds[(dbase + 0) * 68 + nn], O_lds[(dbase + 1) * 68 + nn]);
            u1 = pk2(O_lds[(dbase + 2) * 68 + nn], O_lds[(dbase + 3) * 68 + nn]);
            u2 = pk2(O_lds[(dbase + 4) * 68 + nn], O_lds[(dbase + 5) * 68 + nn]);
            u3 = pk2(O_lds[(dbase + 6) * 68 + nn], O_lds[(dbase + 7) * 68 + nn]);
        }
        uint4 uu; uu.x = u0; uu.y = u1; uu.z = u2; uu.w = u3;
        af[ck] = *(bf16x8*)&uu;
    }
    f32x16 P;
    #pragma unroll
    for (int i = 0; i < 16; ++i) P[i] = 0.f;
    {
        const short* wp = wbF + jq * 4096;
        #pragma unroll
        for (int ck = 0; ck < 8; ++ck) {
            bf16x8 bf = *(const bf16x8*)(wp + (2 * ck + hi) * 256 + l5 * 8);
            P = __builtin_amdgcn_mfma_f32_32x32x16_bf16(af[ck], bf, P, 0, 0, 0);
        }
    }
    float pbj = pb[jq * 32 + l5];
    __syncthreads();   // O_lds reads complete before overwrite
    float* Plds = (float*)smem;                        // [64 n][132 j]
    #pragma unroll
    for (int i = 0; i < 16; ++i) {
        int roff = (i & 3) + 8 * (i >> 2) + 4 * hi;
        Plds[(nh2 * 32 + roff) * 132 + jq * 32 + l5] = P[i] + pbj;
    }
    __syncthreads();

    {
        int row = tid >> 3, part = tid & 7;
        const float* xr = x + ((size_t)b * NN + n0 + row) * DD + part * 16;
        float y[16];
        float sum = 0.f, ss = 0.f;
        #pragma unroll
        for (int c = 0; c < 4; ++c) {
            float4 pv = *(const float4*)(Plds + row * 132 + part * 16 + c * 4);
            float4 xv = *(const float4*)(xr + c * 4);
            #pragma unroll
            for (int k = 0; k < 4; ++k) {
                float p = ((const float*)&pv)[k];
                float e = (p > 0.f ? p : __expf(p) - 1.f) + ((const float*)&xv)[k];
                y[c * 4 + k] = e;
                sum += e; ss += e * e;
            }
        }
        sum += __shfl_xor(sum, 1); ss += __shfl_xor(ss, 1);
        sum += __shfl_xor(sum, 2); ss += __shfl_xor(ss, 2);
        sum += __shfl_xor(sum, 4); ss += __shfl_xor(ss, 4);
        float mu = sum * 0.0078125f;
        float var = fmaxf(ss * 0.0078125f - mu * mu, 0.f);
        float inv = rsqrtf(var + 1e-5f);
        float* op = out + ((size_t)b * NN + n0 + row) * DD + part * 16;
        #pragma unroll
        for (int c = 0; c < 4; ++c) {
            float4 gv = *(const float4*)(gamma + part * 16 + c * 4);
            float4 bv = *(const float4*)(beta + part * 16 + c * 4);
            float4 o;
            ((float*)&o)[0] = (y[c*4+0] - mu) * inv * ((const float*)&gv)[0] + ((const float*)&bv)[0];
            ((float*)&o)[1] = (y[c*4+1] - mu) * inv * ((const float*)&gv)[1] + ((const float*)&bv)[1];
            ((float*)&o)[2] = (y[c*4+2] - mu) * inv * ((const float*)&gv)[2] + ((const float*)&bv)[2];
            ((float*)&o)[3] = (y[c*4+3] - mu) * inv * ((const float*)&gv)[3] + ((const float*)&bv)[3];
            *(float4*)(op + c * 4) = o;
        }
    }
}

extern "C" void kernel_launch(void* const* d_in, const int* in_sizes, int n_in,
                              void* d_out, int out_size, void* d_ws, size_t ws_size,
                              hipStream_t stream) {
    const float* x  = (const float*)d_in[0];
    const float* ls = (const float*)d_in[1];
    const float* pw = (const float*)d_in[2];
    const float* pb = (const float*)d_in[3];
    const float* g  = (const float*)d_in[4];
    const float* be = (const float*)d_in[5];
    float* out = (float*)d_out;

    char* ws = (char*)d_ws;
    short* xbF = (short*)ws;                                       // 4 MB
    short* vF  = (short*)(ws + (size_t)4 * 1024 * 1024);           // 4 MB
    float* x2  = (float*)(ws + (size_t)8 * 1024 * 1024);           // 64 KB
    short* wbF = (short*)(ws + (size_t)8 * 1024 * 1024 + 65536);   // 32 KB

    prep_kernel<<<dim3(264), dim3(512), 0, stream>>>(x, pw, xbF, vF, wbF, x2);
    attn_kernel<<<dim3(BB * NN / 64), dim3(512), 0, stream>>>(
        xbF, vF, x2, wbF, ls, pb, x, g, be, out);
}

// Round 7
// 50.175 us; speedup vs baseline: 1.1534x; 1.1534x over previous
//
#include <hip/hip_runtime.h>
#include <hip/hip_bf16.h>

#define BB 4
#define NN 4096
#define DD 128

typedef __attribute__((ext_vector_type(8))) short bf16x8;
typedef __attribute__((ext_vector_type(16))) float f32x16;

__device__ __forceinline__ unsigned short f2bf(float f) {
    unsigned u = __float_as_uint(f);
    return (unsigned short)((u + 0x7FFFu + ((u >> 16) & 1u)) >> 16);
}
__device__ __forceinline__ float bf2f(unsigned short s) {
    return __uint_as_float((unsigned)s << 16);
}
__device__ __forceinline__ unsigned pk2(float a, float b) {
    return (unsigned)f2bf(a) | ((unsigned)f2bf(b) << 16);
}

// ---------------------------------------------------------------------------
// Fragment-major layouts (shorts):
//   xbF: row-block rb = n>>5 (global over B*N), granule g = k>>3 (0..15):
//        addr = rb*4096 + g*256 + (n&31)*8 + (k&7)
//   vF:  per batch: d-block db = d>>5, m-granule g = m>>3 (0..511):
//        addr = b*524288 + db*131072 + g*256 + (d&31)*8 + (m&7)
//   wbF: j-block jb = j>>5, granule g = k>>3: jb*4096 + g*256 + (j&31)*8 + (k&7)
// ---------------------------------------------------------------------------

// prep: blocks 0..255 = x->bf16 frag-major (+transpose) + x2; blocks 256..263 = wt
__global__ __launch_bounds__(512) void prep_kernel(const float* __restrict__ x,
        const float* __restrict__ W, short* __restrict__ xbF,
        short* __restrict__ vF, short* __restrict__ wbF, float* __restrict__ x2) {
    if (blockIdx.x >= 256) {
        int t = (blockIdx.x - 256) * 512 + threadIdx.x;   // 0..4095
        int j = t >> 5, cq = t & 31;
        float4 v = *(const float4*)(W + j * 128 + cq * 4);
        uint2 pk; pk.x = pk2(v.x, v.y); pk.y = pk2(v.z, v.w);
        *(uint2*)(wbF + (j >> 5) * 4096 + (cq >> 1) * 256 + (j & 31) * 8 + (cq & 1) * 4) = pk;
        return;
    }
    __shared__ short Ls[64 * 136];
    int tid = threadIdx.x;
    int r = tid >> 3, cq = tid & 7;
    size_t rowg = (size_t)blockIdx.x * 64 + r;
    const float* xp = x + rowg * DD + cq * 16;
    short tmp[16];
    float s = 0.f;
    #pragma unroll
    for (int i = 0; i < 4; ++i) {
        float4 v = ((const float4*)xp)[i];
        unsigned short b0 = f2bf(v.x), b1 = f2bf(v.y), b2 = f2bf(v.z), b3 = f2bf(v.w);
        tmp[i*4+0] = (short)b0; tmp[i*4+1] = (short)b1;
        tmp[i*4+2] = (short)b2; tmp[i*4+3] = (short)b3;
        float f0 = bf2f(b0), f1 = bf2f(b1), f2 = bf2f(b2), f3 = bf2f(b3);
        s += f0*f0 + f1*f1 + f2*f2 + f3*f3;
    }
    #pragma unroll
    for (int c = 0; c < 2; ++c) {
        uint4 v = ((uint4*)tmp)[c];
        *(uint4*)(xbF + (rowg >> 5) * 4096 + (size_t)(cq * 2 + c) * 256 + (rowg & 31) * 8) = v;
        *(uint4*)(&Ls[r * 136 + cq * 16 + c * 8]) = v;
    }
    s += __shfl_xor(s, 1); s += __shfl_xor(s, 2); s += __shfl_xor(s, 4);
    if (cq == 0) x2[rowg] = s;
    __syncthreads();
    int d = tid & 127, q = tid >> 7;
    short arr[16];
    #pragma unroll
    for (int i = 0; i < 16; ++i) arr[i] = Ls[(q * 16 + i) * 136 + d];
    int blk = blockIdx.x, b = blk >> 6;
    int g0 = (blk & 63) * 8 + q * 2;
    size_t base = (size_t)b * 524288 + (size_t)(d >> 5) * 131072 + (size_t)(d & 31) * 8;
    *(uint4*)(vF + base + (size_t)g0 * 256)       = ((uint4*)arr)[0];
    *(uint4*)(vF + base + (size_t)(g0 + 1) * 256) = ((uint4*)arr)[1];
}

// ---------------------------------------------------------------------------
// attn: 256 blocks x 1024 threads (16 waves, 4/SIMD), barrier-free main loop.
// Wave w: n-half nh = w&1 (32 n-rows), slices s = (w>>1) + 8t, t=0..15.
// Live slices (rare) accumulate PV into shared f32 O via LDS atomics.
// ---------------------------------------------------------------------------
__global__ __launch_bounds__(1024, 4) void attn_kernel(
        const short* __restrict__ xbF, const short* __restrict__ vF,
        const float* __restrict__ x2, const short* __restrict__ wbF,
        const float* __restrict__ log_sigmas, const float* __restrict__ pb,
        const float* __restrict__ x, const float* __restrict__ gamma,
        const float* __restrict__ beta, float* __restrict__ out) {
    __shared__ char smem[34816] __attribute__((aligned(128)));
    float* O_lds = (float*)smem;                       // [128 d][68 n]

    int tid = threadIdx.x, lane = tid & 63, w = tid >> 6;
    int l5 = lane & 31, hi = lane >> 5;
    int nh = w & 1, sgrp = w >> 1;

    int bid = (blockIdx.x & 7) * 32 + (blockIdx.x >> 3);  // XCD-bijective
    int b = bid >> 6, n0 = (bid & 63) * 64;

    const short* xf_b = xbF + (size_t)b * 524288;
    const short* vf_b = vF + (size_t)b * 524288;
    const float* x2b = x2 + (size_t)b * NN;

    #pragma unroll
    for (int i = 0; i < 8; ++i) O_lds[tid + 1024 * i] = 0.f;
    if (tid < 512) O_lds[8192 + tid] = 0.f;

    float invd[4];
    #pragma unroll
    for (int h = 0; h < 4; ++h) {
        float sg = __expf(log_sigmas[h]);
        invd[h] = 1.0f / (2.0f * sg * sg + 1e-6f);
    }
    bool same = (invd[0] == invd[1]) && (invd[1] == invd[2]) && (invd[2] == invd[3]);
    float c0 = -invd[0];
    float invd_min = fminf(fminf(invd[0], invd[1]), fminf(invd[2], invd[3]));
    float thr = 30.0f / invd_min;

    // Q fragments for this wave's n-half
    bf16x8 qa[8];
    {
        const short* qp = xf_b + (size_t)((n0 >> 5) + nh) * 4096;
        #pragma unroll
        for (int ck = 0; ck < 8; ++ck)
            qa[ck] = *(const bf16x8*)(qp + (2 * ck + hi) * 256 + l5 * 8);
    }
    float x2n = x2b[n0 + nh * 32 + l5];
    float limit = x2n - thr;

    __syncthreads();   // O_lds zeroed

    for (int t = 0; t < 16; ++t) {
        int s = sgrp + t * 8;          // m-slice 0..127
        // K fragments straight from L2
        const short* kp = xf_b + (size_t)s * 4096;
        bf16x8 kc[8];
        #pragma unroll
        for (int ck = 0; ck < 8; ++ck)
            kc[ck] = *(const bf16x8*)(kp + (2 * ck + hi) * 256 + l5 * 8);
        float4 t0 = *(const float4*)(x2b + s * 32 + 4 * hi);
        float4 t1 = *(const float4*)(x2b + s * 32 + 8 + 4 * hi);
        float4 t2 = *(const float4*)(x2b + s * 32 + 16 + 4 * hi);
        float4 t3 = *(const float4*)(x2b + s * 32 + 24 + 4 * hi);
        float xmv[16];
        xmv[0]=t0.x; xmv[1]=t0.y; xmv[2]=t0.z; xmv[3]=t0.w;
        xmv[4]=t1.x; xmv[5]=t1.y; xmv[6]=t1.z; xmv[7]=t1.w;
        xmv[8]=t2.x; xmv[9]=t2.y; xmv[10]=t2.z; xmv[11]=t2.w;
        xmv[12]=t3.x; xmv[13]=t3.y; xmv[14]=t3.z; xmv[15]=t3.w;

        f32x16 SA;
        #pragma unroll
        for (int i = 0; i < 16; ++i) SA[i] = 0.f;
        #pragma unroll
        for (int ck = 0; ck < 8; ++ck)
            SA = __builtin_amdgcn_mfma_f32_32x32x16_bf16(kc[ck], qa[ck], SA, 0, 0, 0);

        // screen: dist^2 = x2n + x2m - 2S > thr  <=>  2S - x2m < x2n - thr
        float e[16];
        #pragma unroll
        for (int i = 0; i < 16; ++i) e[i] = fmaf(2.0f, SA[i], -xmv[i]);
        float lmax = e[0];
        #pragma unroll
        for (int i = 1; i < 16; ++i) lmax = fmaxf(lmax, e[i]);

        if (__any(lmax >= limit)) {
            float wA[16];
            #pragma unroll
            for (int i = 0; i < 16; ++i) {
                float cA = fmaxf(x2n - e[i], 0.f);
                if (same) wA[i] = __expf(cA * c0);
                else wA[i] = 0.25f * (__expf(-cA * invd[0]) + __expf(-cA * invd[1]) +
                                      __expf(-cA * invd[2]) + __expf(-cA * invd[3]));
            }
            // pack granule quarters; exchange halves across hi (shfl_xor 32)
            unsigned pAlo[4], pAhi[4];
            #pragma unroll
            for (int G = 0; G < 4; ++G) {
                pAlo[G] = pk2(wA[4*G+0], wA[4*G+1]);
                pAhi[G] = pk2(wA[4*G+2], wA[4*G+3]);
            }
            uint4 fA[2];
            #pragma unroll
            for (int ks = 0; ks < 2; ++ks) {
                unsigned oAl = hi ? pAlo[2*ks+1] : pAlo[2*ks];
                unsigned oAh = hi ? pAhi[2*ks+1] : pAhi[2*ks];
                unsigned sAl = hi ? pAlo[2*ks]   : pAlo[2*ks+1];
                unsigned sAh = hi ? pAhi[2*ks]   : pAhi[2*ks+1];
                unsigned rAl = __shfl_xor(sAl, 32);
                unsigned rAh = __shfl_xor(sAh, 32);
                fA[ks].x = hi ? rAl : oAl;  fA[ks].y = hi ? rAh : oAh;
                fA[ks].z = hi ? oAl : rAl;  fA[ks].w = hi ? oAh : rAh;
            }
            bf16x8 wfA0 = *(bf16x8*)&fA[0], wfA1 = *(bf16x8*)&fA[1];
            #pragma unroll
            for (int db = 0; db < 4; ++db) {
                const short* vp = vf_b + db * 131072 + (size_t)s * 4 * 256;
                bf16x8 v0 = *(const bf16x8*)(vp + (size_t)(0 + hi) * 256 + l5 * 8);
                bf16x8 v1 = *(const bf16x8*)(vp + (size_t)(2 + hi) * 256 + l5 * 8);
                f32x16 DA;
                #pragma unroll
                for (int i = 0; i < 16; ++i) DA[i] = 0.f;
                DA = __builtin_amdgcn_mfma_f32_32x32x16_bf16(v0, wfA0, DA, 0, 0, 0);
                DA = __builtin_amdgcn_mfma_f32_32x32x16_bf16(v1, wfA1, DA, 0, 0, 0);
                #pragma unroll
                for (int i = 0; i < 16; ++i) {
                    int droff = (i & 3) + 8 * (i >> 2) + 4 * hi;
                    atomicAdd(&O_lds[(db * 32 + droff) * 68 + nh * 32 + l5], DA[i]);
                }
            }
        }
    }

    __syncthreads();   // all LDS atomics done

    // ---- epilogue: proj MFMA from O_lds (waves 0-7), then ELU + res + LN ----
    if (w < 8) {
        int jq = w & 3, nh2 = w >> 2;
        bf16x8 af[8];
        #pragma unroll
        for (int ck = 0; ck < 8; ++ck) {
            int dbase = ck * 16 + hi * 8;
            int nn = nh2 * 32 + l5;
            uint4 uu;
            uu.x = pk2(O_lds[(dbase + 0) * 68 + nn], O_lds[(dbase + 1) * 68 + nn]);
            uu.y = pk2(O_lds[(dbase + 2) * 68 + nn], O_lds[(dbase + 3) * 68 + nn]);
            uu.z = pk2(O_lds[(dbase + 4) * 68 + nn], O_lds[(dbase + 5) * 68 + nn]);
            uu.w = pk2(O_lds[(dbase + 6) * 68 + nn], O_lds[(dbase + 7) * 68 + nn]);
            af[ck] = *(bf16x8*)&uu;
        }
        f32x16 P;
        #pragma unroll
        for (int i = 0; i < 16; ++i) P[i] = 0.f;
        const short* wp = wbF + jq * 4096;
        #pragma unroll
        for (int ck = 0; ck < 8; ++ck) {
            bf16x8 bf = *(const bf16x8*)(wp + (2 * ck + hi) * 256 + l5 * 8);
            P = __builtin_amdgcn_mfma_f32_32x32x16_bf16(af[ck], bf, P, 0, 0, 0);
        }
        float pbj = pb[jq * 32 + l5];
        __syncthreads();   // O_lds reads complete before overwrite
        float* Plds = (float*)smem;                    // [64 n][132 j]
        #pragma unroll
        for (int i = 0; i < 16; ++i) {
            int roff = (i & 3) + 8 * (i >> 2) + 4 * hi;
            Plds[(nh2 * 32 + roff) * 132 + jq * 32 + l5] = P[i] + pbj;
        }
    } else {
        __syncthreads();
    }
    __syncthreads();

    {
        float* Plds = (float*)smem;
        int row = tid >> 4, part = tid & 15;           // 64 rows, 8 f32 each
        const float* xr = x + ((size_t)b * NN + n0 + row) * DD + part * 8;
        float y[8];
        float sum = 0.f, ss = 0.f;
        #pragma unroll
        for (int c = 0; c < 2; ++c) {
            float4 pv = *(const float4*)(Plds + row * 132 + part * 8 + c * 4);
            float4 xv = *(const float4*)(xr + c * 4);
            #pragma unroll
            for (int k = 0; k < 4; ++k) {
                float p = ((const float*)&pv)[k];
                float e2 = (p > 0.f ? p : __expf(p) - 1.f) + ((const float*)&xv)[k];
                y[c * 4 + k] = e2;
                sum += e2; ss += e2 * e2;
            }
        }
        sum += __shfl_xor(sum, 1); ss += __shfl_xor(ss, 1);
        sum += __shfl_xor(sum, 2); ss += __shfl_xor(ss, 2);
        sum += __shfl_xor(sum, 4); ss += __shfl_xor(ss, 4);
        sum += __shfl_xor(sum, 8); ss += __shfl_xor(ss, 8);
        float mu = sum * 0.0078125f;
        float var = fmaxf(ss * 0.0078125f - mu * mu, 0.f);
        float inv = rsqrtf(var + 1e-5f);
        float* op = out + ((size_t)b * NN + n0 + row) * DD + part * 8;
        #pragma unroll
        for (int c = 0; c < 2; ++c) {
            float4 gv = *(const float4*)(gamma + part * 8 + c * 4);
            float4 bv = *(const float4*)(beta + part * 8 + c * 4);
            float4 o;
            ((float*)&o)[0] = (y[c*4+0] - mu) * inv * ((const float*)&gv)[0] + ((const float*)&bv)[0];
            ((float*)&o)[1] = (y[c*4+1] - mu) * inv * ((const float*)&gv)[1] + ((const float*)&bv)[1];
            ((float*)&o)[2] = (y[c*4+2] - mu) * inv * ((const float*)&gv)[2] + ((const float*)&bv)[2];
            ((float*)&o)[3] = (y[c*4+3] - mu) * inv * ((const float*)&gv)[3] + ((const float*)&bv)[3];
            *(float4*)(op + c * 4) = o;
        }
    }
}

extern "C" void kernel_launch(void* const* d_in, const int* in_sizes, int n_in,
                              void* d_out, int out_size, void* d_ws, size_t ws_size,
                              hipStream_t stream) {
    const float* x  = (const float*)d_in[0];
    const float* ls = (const float*)d_in[1];
    const float* pw = (const float*)d_in[2];
    const float* pb = (const float*)d_in[3];
    const float* g  = (const float*)d_in[4];
    const float* be = (const float*)d_in[5];
    float* out = (float*)d_out;

    char* ws = (char*)d_ws;
    short* xbF = (short*)ws;                                       // 4 MB
    short* vF  = (short*)(ws + (size_t)4 * 1024 * 1024);           // 4 MB
    float* x2  = (float*)(ws + (size_t)8 * 1024 * 1024);           // 64 KB
    short* wbF = (short*)(ws + (size_t)8 * 1024 * 1024 + 65536);   // 32 KB

    prep_kernel<<<dim3(264), dim3(512), 0, stream>>>(x, pw, xbF, vF, wbF, x2);
    attn_kernel<<<dim3(BB * NN / 64), dim3(1024), 0, stream>>>(
        xbF, vF, x2, wbF, ls, pb, x, g, be, out);
}